// Round 7
// baseline (490.995 us; speedup 1.0000x reference)
//
#include <hip/hip_runtime.h>
#include <math.h>

#define LOG2E 1.44269504088896f
#define LN2   0.69314718055995f

// ---------- DPP cross-lane (VALU pipe, no LDS) ----------
// wave_shr1: lane i <- lane i-1; lane 0 <- 0. gfx9 DPP ctrl 0x138.
static __device__ __forceinline__ float wave_shr1(float x) {
  int t = __builtin_amdgcn_update_dpp(0, __float_as_int(x), 0x138, 0xf, 0xf, false);
  return __int_as_float(t);
}
template <int CTRL>
static __device__ __forceinline__ float dppmax(float m) {
  int s = __float_as_int(m);
  int t = __builtin_amdgcn_update_dpp(s, s, CTRL, 0xf, 0xf, false);
  return fmaxf(m, __int_as_float(t));
}
// full-wave max -> broadcast to all lanes (values are >= 0)
static __device__ __forceinline__ float wave_max_bcast(float m) {
  m = dppmax<0x111>(m);  // row_shr:1
  m = dppmax<0x112>(m);  // row_shr:2
  m = dppmax<0x114>(m);  // row_shr:4
  m = dppmax<0x118>(m);  // row_shr:8
  m = dppmax<0x142>(m);  // row_bcast:15
  m = dppmax<0x143>(m);  // row_bcast:31  -> lane 63 has wave max
  return __int_as_float(__builtin_amdgcn_readlane(__float_as_int(m), 63));
}

// Fused gather+DP: linear-domain scaled forward, one wave per batch element.
// Lane l owns states 4l..4l+3 (+ state 256 via lane 63's a4 when HAS5).
// Emissions gathered DIRECTLY from lp each step: blank lp[row][0] + two label
// columns per lane. Prefetch ring = 16 NAMED float triples (48 VGPRs, 48
// outstanding VMEM < vmcnt cap 63) hides HBM latency across ~16 rows.
// CRITICAL (R6 post-mortem): states s >= Sb must be HELD AT ZERO. Without
// masks the invalid diagonal front free-runs ahead of the pinned valid
// states, dominates the rescale max by >> fp32 range, and flushes the valid
// alphas to 0 -> log(0) = inf. Masks mv0..mv3 zero the emission of invalid
// states (exactly R5's emission=0 semantics); rescale max then spans valid
// states only.
template <bool HAS5>
static __device__ __forceinline__ void dp_run(
    const float* lpb, const int* tg, int len, int tl, int l, int C,
    float* outp) {
  const int Sb = 2 * tl + 1;
  // per-lane gather columns + skip masks + validity masks
  const int c0 = tg[2 * l];          // label of state 4l+1
  const int c1 = tg[2 * l + 1];      // label of state 4l+3
  const bool sk1 = (l > 0) ? (c0 != tg[2 * l - 1]) : false;
  const bool sk3 = (c1 != c0);
  const bool mv0 = (4 * l + 0) < Sb;
  const bool mv1 = (4 * l + 1) < Sb;
  const bool mv2 = (4 * l + 2) < Sb;
  const bool mv3 = (4 * l + 3) < Sb;
  // HAS5 -> Sb == 257 -> every state 4l+4 (<=256) is valid, a4 needs no mask.

  float a0, a1, a2, a3, a4;
  {
    // t = 0: only states 0 (blank) and 1 (first label) alive; boost 2^100
    const float pb0 = lpb[0];
    const float v00 = lpb[c0];       // lane 0's c0 == tg[0]
    a0 = (l == 0) ? __builtin_amdgcn_exp2f(fmaf(pb0, LOG2E, 100.f)) : 0.f;
    a1 = (l == 0) ? __builtin_amdgcn_exp2f(fmaf(v00, LOG2E, 100.f)) : 0.f;
    a2 = 0.f; a3 = 0.f; a4 = 0.f;
  }
  int Cexp = -100;
  float up1 = 0.f;                   // alpha[4l-1] from lane l-1
  constexpr int BIAS = 108;          // rescale anchor (p<=1: alphas only decay)

  auto rescale = [&]() {             // zero-staleness, every 8 steps
    float m = fmaxf(fmaxf(a0, a1), fmaxf(a2, a3));
    if (HAS5) m = fmaxf(m, a4);
    const float full = wave_max_bcast(m);
    int e; (void)frexpf(full, &e);   // full==0 -> e=0, alphas stay 0
    const int sh = BIAS - e;
    a0 = ldexpf(a0, sh); a1 = ldexpf(a1, sh);
    a2 = ldexpf(a2, sh); a3 = ldexpf(a3, sh);
    if (HAS5) a4 = ldexpf(a4, sh);
    up1 = ldexpf(up1, sh);
    Cexp += e - BIAS;
  };

// ring slot load: clamped rows are never consumed
#define LOADROW(PB, V0, V1, IDX_)                                   \
  {                                                                 \
    int idx_ = (IDX_); if (idx_ >= len) idx_ = len - 1;             \
    const float* r_ = lpb + (size_t)idx_ * C;                       \
    PB = r_[0]; V0 = r_[c0]; V1 = r_[c1];                           \
  }

// one DP step consuming a ring slot (exp2s depend only on loads, not alphas).
// Emissions of invalid states masked to 0 -> their alphas stay exactly 0.
#define STEP(PB, V0, V1)                                            \
  {                                                                 \
    const float pbv = __builtin_amdgcn_exp2f(PB * LOG2E);           \
    const float pl1 = mv1 ? __builtin_amdgcn_exp2f(V0 * LOG2E) : 0.f; \
    const float pl3 = mv3 ? __builtin_amdgcn_exp2f(V1 * LOG2E) : 0.f; \
    const float pbA = mv0 ? pbv : 0.f;                              \
    const float pbB = mv2 ? pbv : 0.f;                              \
    const float n0 = pbA * (a0 + up1);                              \
    const float n1 = pl1 * (a1 + a0 + (sk1 ? up1 : 0.f));           \
    const float n2 = pbB * (a2 + a1);                               \
    const float n3 = pl3 * (a3 + a2 + (sk3 ? a1 : 0.f));            \
    if (HAS5) a4 = pbv * (a4 + a3);                                 \
    up1 = wave_shr1(n3);                                            \
    a0 = n0; a1 = n1; a2 = n2; a3 = n3;                             \
  }

  // prologue: named ring holds rows 1..16
  float pb0_, va0_, vb0_, pb1_, va1_, vb1_, pb2_, va2_, vb2_, pb3_, va3_, vb3_;
  float pb4_, va4_, vb4_, pb5_, va5_, vb5_, pb6_, va6_, vb6_, pb7_, va7_, vb7_;
  float pb8_, va8_, vb8_, pb9_, va9_, vb9_, pb10_, va10_, vb10_, pb11_, va11_, vb11_;
  float pb12_, va12_, vb12_, pb13_, va13_, vb13_, pb14_, va14_, vb14_, pb15_, va15_, vb15_;
  LOADROW(pb0_, va0_, vb0_, 1)   LOADROW(pb1_, va1_, vb1_, 2)
  LOADROW(pb2_, va2_, vb2_, 3)   LOADROW(pb3_, va3_, vb3_, 4)
  LOADROW(pb4_, va4_, vb4_, 5)   LOADROW(pb5_, va5_, vb5_, 6)
  LOADROW(pb6_, va6_, vb6_, 7)   LOADROW(pb7_, va7_, vb7_, 8)
  LOADROW(pb8_, va8_, vb8_, 9)   LOADROW(pb9_, va9_, vb9_, 10)
  LOADROW(pb10_, va10_, vb10_, 11) LOADROW(pb11_, va11_, vb11_, 12)
  LOADROW(pb12_, va12_, vb12_, 13) LOADROW(pb13_, va13_, vb13_, 14)
  LOADROW(pb14_, va14_, vb14_, 15) LOADROW(pb15_, va15_, vb15_, 16)

  int t = 1;
  for (; t + 15 < len; t += 16) {
    STEP(pb0_, va0_, vb0_)              LOADROW(pb0_, va0_, vb0_, t + 16)
    STEP(pb1_, va1_, vb1_)              LOADROW(pb1_, va1_, vb1_, t + 17)
    STEP(pb2_, va2_, vb2_)              LOADROW(pb2_, va2_, vb2_, t + 18)
    STEP(pb3_, va3_, vb3_)              LOADROW(pb3_, va3_, vb3_, t + 19)
    STEP(pb4_, va4_, vb4_)              LOADROW(pb4_, va4_, vb4_, t + 20)
    STEP(pb5_, va5_, vb5_)              LOADROW(pb5_, va5_, vb5_, t + 21)
    STEP(pb6_, va6_, vb6_)              LOADROW(pb6_, va6_, vb6_, t + 22)
    STEP(pb7_, va7_, vb7_) rescale();   LOADROW(pb7_, va7_, vb7_, t + 23)
    STEP(pb8_, va8_, vb8_)              LOADROW(pb8_, va8_, vb8_, t + 24)
    STEP(pb9_, va9_, vb9_)              LOADROW(pb9_, va9_, vb9_, t + 25)
    STEP(pb10_, va10_, vb10_)           LOADROW(pb10_, va10_, vb10_, t + 26)
    STEP(pb11_, va11_, vb11_)           LOADROW(pb11_, va11_, vb11_, t + 27)
    STEP(pb12_, va12_, vb12_)           LOADROW(pb12_, va12_, vb12_, t + 28)
    STEP(pb13_, va13_, vb13_)           LOADROW(pb13_, va13_, vb13_, t + 29)
    STEP(pb14_, va14_, vb14_)           LOADROW(pb14_, va14_, vb14_, t + 30)
    STEP(pb15_, va15_, vb15_) rescale(); LOADROW(pb15_, va15_, vb15_, t + 31)
  }
  // tail: n = len - t in [0,15], static phases, uniform guards
  if (t + 0 < len)  { STEP(pb0_, va0_, vb0_) }
  if (t + 1 < len)  { STEP(pb1_, va1_, vb1_) }
  if (t + 2 < len)  { STEP(pb2_, va2_, vb2_) }
  if (t + 3 < len)  { STEP(pb3_, va3_, vb3_) }
  if (t + 4 < len)  { STEP(pb4_, va4_, vb4_) }
  if (t + 5 < len)  { STEP(pb5_, va5_, vb5_) }
  if (t + 6 < len)  { STEP(pb6_, va6_, vb6_) }
  if (t + 7 < len)  { STEP(pb7_, va7_, vb7_) rescale(); }
  if (t + 8 < len)  { STEP(pb8_, va8_, vb8_) }
  if (t + 9 < len)  { STEP(pb9_, va9_, vb9_) }
  if (t + 10 < len) { STEP(pb10_, va10_, vb10_) }
  if (t + 11 < len) { STEP(pb11_, va11_, vb11_) }
  if (t + 12 < len) { STEP(pb12_, va12_, vb12_) }
  if (t + 13 < len) { STEP(pb13_, va13_, vb13_) }
  if (t + 14 < len) { STEP(pb14_, va14_, vb14_) }

#undef LOADROW
#undef STEP

  __shared__ float af[257];
  af[4 * l + 0] = a0; af[4 * l + 1] = a1;
  af[4 * l + 2] = a2; af[4 * l + 3] = a3;
  if (HAS5 && l == 63) af[256] = a4;
  __syncthreads();
  if (l == 0) {
    const float s = af[Sb - 1] + af[Sb - 2];
    // alpha_true = af * 2^Cexp; frexp normalizes so v_log never sees a denormal
    int e; const float m = frexpf(s, &e);
    const float llh = (__builtin_amdgcn_logf(m) + (float)(e + Cexp)) * LN2;
    *outp = -llh;
  }
}

__global__ __launch_bounds__(64) void ctc_dp_kernel(
    const float* __restrict__ lp, const int* __restrict__ targets,
    const int* __restrict__ ilen, const int* __restrict__ tlen,
    float* __restrict__ out, int T, int C, int L) {
  const int b = blockIdx.x;
  const int l = threadIdx.x;
  const int len = ilen[b];
  const int tl = tlen[b];
  const int* tg = targets + (size_t)b * L;
  const float* lpb = lp + (size_t)b * T * C;
  if (tl >= L) dp_run<true>(lpb, tg, len, tl, l, C, out + b);   // state 256 live
  else         dp_run<false>(lpb, tg, len, tl, l, C, out + b);
}

extern "C" void kernel_launch(void* const* d_in, const int* in_sizes, int n_in,
                              void* d_out, int out_size, void* d_ws, size_t ws_size,
                              hipStream_t stream) {
  const float* lp = (const float*)d_in[0];
  const int* targets = (const int*)d_in[1];
  const int* ilen = (const int*)d_in[2];
  const int* tlen = (const int*)d_in[3];
  float* out = (float*)d_out;

  const int B = in_sizes[2];               // 32
  const int L = in_sizes[1] / B;           // 128
  const int C = 1024;                      // per reference
  const int T = in_sizes[0] / (B * C);     // 1600

  (void)d_ws; (void)ws_size;               // fused: no workspace needed

  ctc_dp_kernel<<<B, 64, 0, stream>>>(lp, targets, ilen, tlen, out, T, C, L);
}

// Round 8
// 371.598 us; speedup vs baseline: 1.3213x; 1.3213x over previous
//
#include <hip/hip_runtime.h>
#include <math.h>

#define LOG2E 1.44269504088896f
#define LN2   0.69314718055995f

// ---------- DPP cross-lane (VALU pipe, no LDS) ----------
// wave_shr1: lane i <- lane i-1; lane 0 <- 0. gfx9 DPP ctrl 0x138.
static __device__ __forceinline__ float wave_shr1(float x) {
  int t = __builtin_amdgcn_update_dpp(0, __float_as_int(x), 0x138, 0xf, 0xf, false);
  return __int_as_float(t);
}
template <int CTRL>
static __device__ __forceinline__ float dppmax(float m) {
  int s = __float_as_int(m);
  int t = __builtin_amdgcn_update_dpp(s, s, CTRL, 0xf, 0xf, false);
  return fmaxf(m, __int_as_float(t));
}
// full-wave max -> broadcast to all lanes (values are >= 0)
static __device__ __forceinline__ float wave_max_bcast(float m) {
  m = dppmax<0x111>(m);  // row_shr:1
  m = dppmax<0x112>(m);  // row_shr:2
  m = dppmax<0x114>(m);  // row_shr:4
  m = dppmax<0x118>(m);  // row_shr:8
  m = dppmax<0x142>(m);  // row_bcast:15
  m = dppmax<0x143>(m);  // row_bcast:31  -> lane 63 has wave max
  return __int_as_float(__builtin_amdgcn_readlane(__float_as_int(m), 63));
}

// Fused gather+DP, R8: asm-pinned prefetch pipeline.
// R7 post-mortem: VGPR_Count=36 proved the named-register ring was sunk by
// the backend scheduler (max-occupancy pressure target) -> depth-1 pipeline,
// 428 cy/step of exposed memory latency. Fix: issue ring loads as asm
// volatile global_load_dword (issue order pinned, "=v" forces VGPR
// residency), consume under counted s_waitcnt vmcnt(45) (= 48 outstanding
// minus the 3 oldest) + sched_barrier(0) (rule #18: compiler hoists
// register-only consumers past inline-asm waitcnt otherwise).
// __launch_bounds__(64,1): 1 wave/EU floor -> 256-VGPR budget, no spills
// (occupancy is irrelevant: only 32 waves exist GPU-wide).
template <bool HAS5>
static __device__ __forceinline__ void dp_run(
    const float* lpb, const int* tg, int len, int tl, int l,
    float* outp) {
  const int Sb = 2 * tl + 1;
  // per-lane gather columns + skip masks + validity masks
  const int c0 = tg[2 * l];          // label of state 4l+1
  const int c1 = tg[2 * l + 1];      // label of state 4l+3
  const bool sk1 = (l > 0) ? (c0 != tg[2 * l - 1]) : false;
  const bool sk3 = (c1 != c0);
  const bool mv0 = (4 * l + 0) < Sb;
  const bool mv1 = (4 * l + 1) < Sb;
  const bool mv2 = (4 * l + 2) < Sb;
  const bool mv3 = (4 * l + 3) < Sb;
  // HAS5 -> Sb == 257 -> every state 4l+4 (<=256) is valid, a4 needs no mask.

  const unsigned oc0 = (unsigned)c0 << 2;   // per-lane byte offsets in a row
  const unsigned oc1 = (unsigned)c1 << 2;

  float a0, a1, a2, a3, a4;
  {
    // t = 0: only states 0 (blank) and 1 (first label) alive; boost 2^100
    const float pb0 = lpb[0];
    const float v00 = lpb[c0];       // lane 0's c0 == tg[0]
    a0 = (l == 0) ? __builtin_amdgcn_exp2f(fmaf(pb0, LOG2E, 100.f)) : 0.f;
    a1 = (l == 0) ? __builtin_amdgcn_exp2f(fmaf(v00, LOG2E, 100.f)) : 0.f;
    a2 = 0.f; a3 = 0.f; a4 = 0.f;
  }
  int Cexp = -100;
  float up1 = 0.f;                   // alpha[4l-1] from lane l-1
  constexpr int BIAS = 108;          // rescale anchor (p<=1: alphas only decay)

  auto rescale = [&]() {             // zero-staleness, every 8 steps, pure VALU
    float m = fmaxf(fmaxf(a0, a1), fmaxf(a2, a3));
    if (HAS5) m = fmaxf(m, a4);
    const float full = wave_max_bcast(m);
    int e; (void)frexpf(full, &e);   // full==0 -> e=0, alphas stay 0
    const int sh = BIAS - e;
    a0 = ldexpf(a0, sh); a1 = ldexpf(a1, sh);
    a2 = ldexpf(a2, sh); a3 = ldexpf(a3, sh);
    if (HAS5) a4 = ldexpf(a4, sh);
    up1 = ldexpf(up1, sh);
    Cexp += e - BIAS;
  };

// asm-pinned load: issue order preserved among volatiles; "=v" forces VGPR.
// C == 1024 floats/row -> row byte stride 4096 (launcher hardcodes C=1024).
#define GLOAD(DST, VOFF)                                            \
  asm volatile("global_load_dword %0, %1, %2"                       \
               : "=v"(DST) : "v"(VOFF), "s"(lpb) : "memory");

// issue one ring slot (3 loads); clamped rows are never consumed
#define ISSUE(PB, V0, V1, IDX_)                                     \
  {                                                                 \
    int idx_ = (IDX_); if (idx_ >= len) idx_ = len - 1;             \
    const unsigned ob_ = (unsigned)idx_ << 12;                      \
    GLOAD(PB, ob_)                                                  \
    GLOAD(V0, ob_ + oc0)                                            \
    GLOAD(V1, ob_ + oc1)                                            \
  }

// one DP step consuming a ring slot (exp2s depend only on loads, not alphas).
// Emissions of invalid states masked to 0 -> their alphas stay exactly 0
// (R6 post-mortem: unmasked invalid front dominates rescale max -> flush).
#define STEP(PB, V0, V1)                                            \
  {                                                                 \
    const float pbv = __builtin_amdgcn_exp2f(PB * LOG2E);           \
    const float pl1 = mv1 ? __builtin_amdgcn_exp2f(V0 * LOG2E) : 0.f; \
    const float pl3 = mv3 ? __builtin_amdgcn_exp2f(V1 * LOG2E) : 0.f; \
    const float pbA = mv0 ? pbv : 0.f;                              \
    const float pbB = mv2 ? pbv : 0.f;                              \
    const float n0 = pbA * (a0 + up1);                              \
    const float n1 = pl1 * (a1 + a0 + (sk1 ? up1 : 0.f));           \
    const float n2 = pbB * (a2 + a1);                               \
    const float n3 = pl3 * (a3 + a2 + (sk3 ? a1 : 0.f));            \
    if (HAS5) a4 = pbv * (a4 + a3);                                 \
    up1 = wave_shr1(n3);                                            \
    a0 = n0; a1 = n1; a2 = n2; a3 = n3;                             \
  }

// phase: wait for the 3 oldest loads (48 in flight -> 45), fence the
// scheduler, consume, then refill the slot 16 rows ahead.
#define PHASE(PB, V0, V1, D)                                        \
  {                                                                 \
    asm volatile("s_waitcnt vmcnt(45)" ::: "memory");               \
    __builtin_amdgcn_sched_barrier(0);                              \
    STEP(PB, V0, V1)                                                \
    ISSUE(PB, V0, V1, t + 16 + (D))                                 \
  }

  // ring registers
  float pb0_, va0_, vb0_, pb1_, va1_, vb1_, pb2_, va2_, vb2_, pb3_, va3_, vb3_;
  float pb4_, va4_, vb4_, pb5_, va5_, vb5_, pb6_, va6_, vb6_, pb7_, va7_, vb7_;
  float pb8_, va8_, vb8_, pb9_, va9_, vb9_, pb10_, va10_, vb10_, pb11_, va11_, vb11_;
  float pb12_, va12_, vb12_, pb13_, va13_, vb13_, pb14_, va14_, vb14_, pb15_, va15_, vb15_;

  // drain all compiler-issued loads so vmcnt counts only the asm pipeline
  asm volatile("s_waitcnt vmcnt(0)" ::: "memory");
  __builtin_amdgcn_sched_barrier(0);

  // prologue: issue rows 1..16 (48 loads in flight)
  ISSUE(pb0_, va0_, vb0_, 1)   ISSUE(pb1_, va1_, vb1_, 2)
  ISSUE(pb2_, va2_, vb2_, 3)   ISSUE(pb3_, va3_, vb3_, 4)
  ISSUE(pb4_, va4_, vb4_, 5)   ISSUE(pb5_, va5_, vb5_, 6)
  ISSUE(pb6_, va6_, vb6_, 7)   ISSUE(pb7_, va7_, vb7_, 8)
  ISSUE(pb8_, va8_, vb8_, 9)   ISSUE(pb9_, va9_, vb9_, 10)
  ISSUE(pb10_, va10_, vb10_, 11) ISSUE(pb11_, va11_, vb11_, 12)
  ISSUE(pb12_, va12_, vb12_, 13) ISSUE(pb13_, va13_, vb13_, 14)
  ISSUE(pb14_, va14_, vb14_, 15) ISSUE(pb15_, va15_, vb15_, 16)

  int t = 1;
  for (; t + 15 < len; t += 16) {
    PHASE(pb0_, va0_, vb0_, 0)
    PHASE(pb1_, va1_, vb1_, 1)
    PHASE(pb2_, va2_, vb2_, 2)
    PHASE(pb3_, va3_, vb3_, 3)
    PHASE(pb4_, va4_, vb4_, 4)
    PHASE(pb5_, va5_, vb5_, 5)
    PHASE(pb6_, va6_, vb6_, 6)
    PHASE(pb7_, va7_, vb7_, 7)   rescale();
    PHASE(pb8_, va8_, vb8_, 8)
    PHASE(pb9_, va9_, vb9_, 9)
    PHASE(pb10_, va10_, vb10_, 10)
    PHASE(pb11_, va11_, vb11_, 11)
    PHASE(pb12_, va12_, vb12_, 12)
    PHASE(pb13_, va13_, vb13_, 13)
    PHASE(pb14_, va14_, vb14_, 14)
    PHASE(pb15_, va15_, vb15_, 15) rescale();
  }

  // tail: drain once, then consume remaining slots (<= 15 rows)
  asm volatile("s_waitcnt vmcnt(0)" ::: "memory");
  __builtin_amdgcn_sched_barrier(0);
  if (t + 0 < len)  { STEP(pb0_, va0_, vb0_) }
  if (t + 1 < len)  { STEP(pb1_, va1_, vb1_) }
  if (t + 2 < len)  { STEP(pb2_, va2_, vb2_) }
  if (t + 3 < len)  { STEP(pb3_, va3_, vb3_) }
  if (t + 4 < len)  { STEP(pb4_, va4_, vb4_) }
  if (t + 5 < len)  { STEP(pb5_, va5_, vb5_) }
  if (t + 6 < len)  { STEP(pb6_, va6_, vb6_) }
  if (t + 7 < len)  { STEP(pb7_, va7_, vb7_) rescale(); }
  if (t + 8 < len)  { STEP(pb8_, va8_, vb8_) }
  if (t + 9 < len)  { STEP(pb9_, va9_, vb9_) }
  if (t + 10 < len) { STEP(pb10_, va10_, vb10_) }
  if (t + 11 < len) { STEP(pb11_, va11_, vb11_) }
  if (t + 12 < len) { STEP(pb12_, va12_, vb12_) }
  if (t + 13 < len) { STEP(pb13_, va13_, vb13_) }
  if (t + 14 < len) { STEP(pb14_, va14_, vb14_) }

#undef PHASE
#undef STEP
#undef ISSUE
#undef GLOAD

  __shared__ float af[257];
  af[4 * l + 0] = a0; af[4 * l + 1] = a1;
  af[4 * l + 2] = a2; af[4 * l + 3] = a3;
  if (HAS5 && l == 63) af[256] = a4;
  __syncthreads();
  if (l == 0) {
    const float s = af[Sb - 1] + af[Sb - 2];
    // alpha_true = af * 2^Cexp; frexp normalizes so v_log never sees a denormal
    int e; const float m = frexpf(s, &e);
    const float llh = (__builtin_amdgcn_logf(m) + (float)(e + Cexp)) * LN2;
    *outp = -llh;
  }
}

__global__ __launch_bounds__(64, 1) void ctc_dp_kernel(
    const float* __restrict__ lp, const int* __restrict__ targets,
    const int* __restrict__ ilen, const int* __restrict__ tlen,
    float* __restrict__ out, int T, int C, int L) {
  const int b = blockIdx.x;
  const int l = threadIdx.x;
  const int len = ilen[b];
  const int tl = tlen[b];
  const int* tg = targets + (size_t)b * L;
  const float* lpb = lp + (size_t)b * T * C;
  if (tl >= L) dp_run<true>(lpb, tg, len, tl, l, out + b);   // state 256 live
  else         dp_run<false>(lpb, tg, len, tl, l, out + b);
}

extern "C" void kernel_launch(void* const* d_in, const int* in_sizes, int n_in,
                              void* d_out, int out_size, void* d_ws, size_t ws_size,
                              hipStream_t stream) {
  const float* lp = (const float*)d_in[0];
  const int* targets = (const int*)d_in[1];
  const int* ilen = (const int*)d_in[2];
  const int* tlen = (const int*)d_in[3];
  float* out = (float*)d_out;

  const int B = in_sizes[2];               // 32
  const int L = in_sizes[1] / B;           // 128
  const int C = 1024;                      // per reference (row stride 4096 B)
  const int T = in_sizes[0] / (B * C);     // 1600

  (void)d_ws; (void)ws_size;               // fused: no workspace needed

  ctc_dp_kernel<<<B, 64, 0, stream>>>(lp, targets, ilen, tlen, out, T, C, L);
}